// Round 2
// baseline (1027.096 us; speedup 1.0000x reference)
//
#include <hip/hip_runtime.h>
#include <math.h>

// Problem constants: B=4, L=512, D=512, H=8, Dh=64
#define L_SEQ 512
#define D_MOD 512
#define N_H   8
#define D_H   64

// ---------------------------------------------------------------------------
// Kernel 1: fused projection GEMM.
// A = inputs [2048 x 512] row-major (f32).
// blockIdx.y selects which weight/output: tiles 0-7 -> Wq/Q, 8-15 -> Wk/K,
// 16-23 -> Wv/V, 24 -> Wp/P (N=24).
// BM=64, BN=64, BK=16, 256 threads, 4x4 per-thread microtile.
// ---------------------------------------------------------------------------
__global__ __launch_bounds__(256) void proj_gemm_kernel(
    const float* __restrict__ A,
    const float* __restrict__ Wq, const float* __restrict__ Wk,
    const float* __restrict__ Wv, const float* __restrict__ Wp,
    float* __restrict__ Q, float* __restrict__ K,
    float* __restrict__ V, float* __restrict__ P)
{
    __shared__ __align__(16) float As[16][68];  // [k][m], padded
    __shared__ __align__(16) float Bs[16][68];  // [k][n]

    const int tid = threadIdx.x;
    const int m0  = blockIdx.x * 64;
    const int nt  = blockIdx.y;

    const float* W; float* C; int ldb, n0, ncols;
    if (nt < 8)       { W = Wq; C = Q; ldb = 512; n0 = nt * 64;        ncols = 512; }
    else if (nt < 16) { W = Wk; C = K; ldb = 512; n0 = (nt - 8) * 64;  ncols = 512; }
    else if (nt < 24) { W = Wv; C = V; ldb = 512; n0 = (nt - 16) * 64; ncols = 512; }
    else              { W = Wp; C = P; ldb = 24;  n0 = 0;              ncols = 24;  }

    const int tx = tid & 15;        // n-group
    const int ty = tid >> 4;        // m-group
    const int am = tid >> 2;        // A-load row   (0..63)
    const int ak = (tid & 3) * 4;   // A-load k4    (0,4,8,12)
    const int bk = tid >> 4;        // B-load row   (0..15)
    const int bn = (tid & 15) * 4;  // B-load col4  (0..60)

    float acc[4][4] = {};

    for (int k0 = 0; k0 < D_MOD; k0 += 16) {
        // stage loads in registers
        float4 av = *(const float4*)&A[(size_t)(m0 + am) * D_MOD + k0 + ak];
        float4 bv;
        if (ncols == 512 || bn + 3 < 24) {
            bv = *(const float4*)&W[(size_t)(k0 + bk) * ldb + n0 + bn];
        } else {
            bv.x = bv.y = bv.z = bv.w = 0.f;
        }

        __syncthreads();   // previous tile's compute done
        // A transposed into LDS
        As[ak + 0][am] = av.x;
        As[ak + 1][am] = av.y;
        As[ak + 2][am] = av.z;
        As[ak + 3][am] = av.w;
        *(float4*)&Bs[bk][bn] = bv;
        __syncthreads();

        #pragma unroll
        for (int kk = 0; kk < 16; ++kk) {
            float4 a = *(const float4*)&As[kk][ty * 4];
            float4 b = *(const float4*)&Bs[kk][tx * 4];
            const float aa[4] = {a.x, a.y, a.z, a.w};
            const float bb[4] = {b.x, b.y, b.z, b.w};
            #pragma unroll
            for (int i = 0; i < 4; ++i)
                #pragma unroll
                for (int j = 0; j < 4; ++j)
                    acc[i][j] = fmaf(aa[i], bb[j], acc[i][j]);
        }
    }

    if (ncols == 512) {
        #pragma unroll
        for (int i = 0; i < 4; ++i) {
            float4 o; o.x = acc[i][0]; o.y = acc[i][1]; o.z = acc[i][2]; o.w = acc[i][3];
            *(float4*)&C[(size_t)(m0 + ty * 4 + i) * 512 + n0 + tx * 4] = o;
        }
    } else {
        #pragma unroll
        for (int i = 0; i < 4; ++i)
            #pragma unroll
            for (int j = 0; j < 4; ++j) {
                int c = tx * 4 + j;
                if (c < 24) C[(size_t)(m0 + ty * 4 + i) * 24 + c] = acc[i][j];
            }
    }
}

// ---------------------------------------------------------------------------
// Kernel 2: the scan. One wave per (b, h, d) state row; lane = e.
// 2048 waves = 512 blocks x 256 threads.
// ---------------------------------------------------------------------------
__global__ __launch_bounds__(256) void scan_kernel(
    const float* __restrict__ Q, const float* __restrict__ K,
    const float* __restrict__ V, const float* __restrict__ P,
    const float* __restrict__ bp,
    const float* __restrict__ prev_state, const float* __restrict__ prev_mom,
    float* __restrict__ out)
{
    const int wid  = blockIdx.x * 4 + (threadIdx.x >> 6);
    const int lane = threadIdx.x & 63;           // e
    const int d    = wid & 63;
    const int h    = (wid >> 6) & 7;
    const int b    = wid >> 9;
    const int bh   = b * N_H + h;

    float st = prev_state[((size_t)bh * 64 + d) * 64 + lane];
    float mo = prev_mom  [((size_t)bh * 64 + d) * 64 + lane];

    const float ba = bp[h], be = bp[8 + h], btt = bp[16 + h];

    const float* qp = Q + (size_t)b * L_SEQ * 512 + h * 64;
    const float* kp = K + (size_t)b * L_SEQ * 512 + h * 64;
    const float* vp = V + (size_t)b * L_SEQ * 512 + h * 64 + d;
    const float* pp = P + (size_t)b * L_SEQ * 24;

    float* ro = out + (size_t)b * L_SEQ * 512 + h * 64 + d;                     // readout
    float* so = out + 1048576ull + (size_t)b * L_SEQ * 32768ull + h * 4096 + d * 64 + lane;
    float* mout = so + 67108864ull;

    // prefetch t=0
    float q  = qp[lane];
    float k  = kp[lane];
    float v  = vp[0];
    float pa = pp[h], pe = pp[8 + h], pt = pp[16 + h];

    for (int t = 0; t < L_SEQ; ++t) {
        // prefetch t+1 (clamped) — independent of the dependency chain below
        const int tn = (t + 1 < L_SEQ) ? t + 1 : t;
        float qn  = qp[(size_t)tn * 512 + lane];
        float kn2 = kp[(size_t)tn * 512 + lane];
        float vn  = vp[(size_t)tn * 512];
        float pan = pp[(size_t)tn * 24 + h];
        float pen = pp[(size_t)tn * 24 + 8 + h];
        float ptn = pp[(size_t)tn * 24 + 16 + h];

        // fused 3-way butterfly reduction: k*k, state.q, state.k
        float r0 = k * k;
        float r1 = st * q;
        float r2 = st * k;
        #pragma unroll
        for (int m = 1; m < 64; m <<= 1) {
            r0 += __shfl_xor(r0, m, 64);
            r1 += __shfl_xor(r1, m, 64);
            r2 += __shfl_xor(r2, m, 64);
        }

        const float inv   = 1.0f / fmaxf(sqrtf(r0), 1e-12f);
        const float y     = r1;              // uses state BEFORE update
        const float vhat  = r2 * inv;
        const float khat  = k * inv;

        const float alpha = 1.0f / (1.0f + expf(-(pa + ba)));
        const float eta   = 1.0f / (1.0f + expf(-(pe + be)));
        const float xt    = pt + btt;
        const float theta = fmaxf(xt, 0.0f) + log1pf(expf(-fabsf(xt)));

        const float grad = (vhat - v) * khat;
        mo = eta * mo - theta * grad;
        st = (1.0f - alpha) * st + mo;

        so  [(size_t)t * 32768ull] = st;
        mout[(size_t)t * 32768ull] = mo;
        if (lane == 0) ro[(size_t)t * 512] = y;

        q = qn; k = kn2; v = vn; pa = pan; pe = pen; pt = ptn;
    }
}

// ---------------------------------------------------------------------------
extern "C" void kernel_launch(void* const* d_in, const int* in_sizes, int n_in,
                              void* d_out, int out_size, void* d_ws, size_t ws_size,
                              hipStream_t stream)
{
    const float* inputs   = (const float*)d_in[0];
    const float* prev_st  = (const float*)d_in[1];
    const float* prev_mom = (const float*)d_in[2];
    const float* Wq       = (const float*)d_in[3];
    const float* Wk       = (const float*)d_in[4];
    const float* Wv       = (const float*)d_in[5];
    const float* Wp       = (const float*)d_in[6];
    const float* bp       = (const float*)d_in[7];

    float* ws = (float*)d_ws;
    float* Q = ws;                 // 2048*512
    float* K = ws + 1048576;       // 2048*512
    float* V = ws + 2097152;       // 2048*512
    float* P = ws + 3145728;       // 2048*24

    dim3 g1(32, 25);
    proj_gemm_kernel<<<g1, dim3(256), 0, stream>>>(inputs, Wq, Wk, Wv, Wp, Q, K, V, P);

    scan_kernel<<<dim3(512), dim3(256), 0, stream>>>(Q, K, V, P, bp, prev_st, prev_mom,
                                                     (float*)d_out);
}